// Round 8
// baseline (190.792 us; speedup 1.0000x reference)
//
#include <hip/hip_runtime.h>
#include <cstdint>
#include <cstddef>

#define B_  32
#define CIN 128
#define P_  256
#define E_  512
#define H_  64
#define W_  64
#define HO  32
#define WO  32
#define PS  65          // padded abits stride (rows/cols -1..63)
#define PN  4225        // 65*65 uint4 entries per image

// ---------------- K1: merged bias GEMMs + weight prep + boundary-correction table ----------------
__global__ void k_bw(const float* __restrict__ emb,
                     const float* __restrict__ m1_w, const float* __restrict__ m1_b,
                     const float* __restrict__ m2_w, const float* __restrict__ m2_b,
                     const float* __restrict__ m3_w, const float* __restrict__ m3_b,
                     const float* __restrict__ conv_w,
                     float* __restrict__ b1, float* __restrict__ b2, float* __restrict__ b3,
                     float* __restrict__ sf, unsigned int* __restrict__ wbits,
                     int4* __restrict__ ctab,
                     float* __restrict__ s1, float* __restrict__ s2) {
    __shared__ float sred[4];
    __shared__ int spop[4][9];
    int bid = blockIdx.x;
    int tid = threadIdx.x;
    int wave = tid >> 6, lane = tid & 63;

    if (bid < B_ * 160) {
        // ---- bias path: wave-per-row, silu inline ----
        int n = bid / 160, rg = bid % 160;
        int row = rg * 4 + wave;         // 0..639
        const float* sp = emb + n * E_;
        const float* wrow; float bias; float* dst;
        if (row < CIN)            { wrow = m1_w + (size_t)row * E_;          bias = m1_b[row]; dst = b1 + n * CIN + row; }
        else if (row < CIN + P_)  { int c = row - CIN;      wrow = m2_w + (size_t)c * E_; bias = m2_b[c]; dst = b2 + n * P_ + c; }
        else                      { int c = row - CIN - P_; wrow = m3_w + (size_t)c * E_; bias = m3_b[c]; dst = b3 + n * P_ + c; }
        float acc = 0.f;
        #pragma unroll
        for (int j = 0; j < 8; j++) {
            int k = j * 64 + lane;
            float e = sp[k];
            acc += (e / (1.f + expf(-e))) * wrow[k];
        }
        #pragma unroll
        for (int off = 32; off > 0; off >>= 1) acc += __shfl_down(acc, off);
        if (lane == 0) *dst = acc + bias;
        return;
    }

    // ---- weight-prep path: 2 out-channels per block ----
    int base = (bid - B_ * 160) * 2;
    int oc = base + (wave >> 1);
    int iw = wave & 1;                   // which 64-channel half
    int i  = iw * 64 + lane;             // input channel 0..127
    if (lane == 0 && iw == 0) { s1[oc] = 0.f; s2[oc] = 0.f; }
    const float* wp = conv_w + ((size_t)oc * CIN + i) * 9;
    float w[9]; float s = 0.f;
    #pragma unroll
    for (int t = 0; t < 9; t++) { w[t] = wp[t]; s += fabsf(w[t]); }
    #pragma unroll
    for (int t = 0; t < 9; t++) {
        unsigned long long m = __ballot(w[t] < 0.f);
        if (lane == 0) {
            wbits[oc * 36 + t * 4 + iw * 2 + 0] = (unsigned int)(m & 0xffffffffull);
            wbits[oc * 36 + t * 4 + iw * 2 + 1] = (unsigned int)(m >> 32);
            spop[wave][t] = __popcll(m);
        }
    }
    #pragma unroll
    for (int off = 32; off > 0; off >>= 1) s += __shfl_down(s, off);
    if (lane == 0) sred[wave] = s;
    __syncthreads();
    if (tid == 0) {
        sf[base]     = (sred[0] + sred[1]) / 1152.f;
        sf[base + 1] = (sred[2] + sred[3]) / 1152.f;
        #pragma unroll
        for (int j = 0; j < 2; j++) {
            int tv[9];
            #pragma unroll
            for (int t = 0; t < 9; t++) tv[t] = 128 - 2 * (spop[2 * j][t] + spop[2 * j + 1][t]);
            int Cr = tv[0] + tv[1] + tv[2];   // top-row taps (kh=0), invalid iff oh==0
            int Cc = tv[0] + tv[3] + tv[6];   // left-col taps (kw=0), invalid iff ow==0
            ctab[base + j] = make_int4(Cr, Cc, tv[0], 0);
        }
    }
}

// ---------------- K2: fused sign(x+b1) bit-pack (padded halo layout) + 2x2 avgpool ----------------
// grid: bid = n*32 + h2. Block covers x rows {2*h2, 2*h2+1}, all 128 ch.
__global__ void k_prep(const float* __restrict__ x, const float* __restrict__ b1,
                       unsigned int* __restrict__ abits, float* __restrict__ xpool) {
    __shared__ float sb1[CIN];
    int n = blockIdx.x >> 5, h2 = blockIdx.x & 31;
    int tid = threadIdx.x;
    for (int i = tid; i < CIN; i += 256) sb1[i] = b1[n * CIN + i];

    // zero halo: padded row 0 (once, by h2==0 blocks) + padded col 0 for this block's 2 rows
    uint4* ab4 = ((uint4*)abits) + (size_t)n * PN;
    if (h2 == 0 && tid < PS) ab4[tid] = make_uint4(0u, 0u, 0u, 0u);
    if (tid < 2) ab4[(2 * h2 + 1 + tid) * PS] = make_uint4(0u, 0u, 0u, 0u);
    __syncthreads();

    // part A: abits (padded index (h+1)*65 + (w+1))
    int pix = tid >> 1, half = tid & 1;
    int h = 2 * h2 + (pix >> 6), w = pix & 63;
    const float* xp = x + ((size_t)n * CIN + half * 64) * (H_ * W_) + (size_t)h * W_ + w;
    unsigned int wds[2];
    #pragma unroll
    for (int wd = 0; wd < 2; wd++) {
        unsigned int m = 0;
        #pragma unroll
        for (int b = 0; b < 32; b++) {
            float v = xp[(size_t)(wd * 32 + b) * (H_ * W_)] + sb1[half * 64 + wd * 32 + b];
            m |= (v < 0.f ? 1u : 0u) << b;
        }
        wds[wd] = m;
    }
    ((uint2*)abits)[((size_t)n * PN + (size_t)(h + 1) * PS + (w + 1)) * 2 + half] = make_uint2(wds[0], wds[1]);

    // part B: avgpool from the same (L2-resident) rows
    for (int idx = tid; idx < CIN * WO; idx += 256) {
        int c = idx >> 5, w2 = idx & 31;
        const float* p = x + ((size_t)n * CIN + c) * (H_ * W_) + (size_t)(2 * h2) * W_ + 2 * w2;
        float2 a = *(const float2*)p;
        float2 b = *(const float2*)(p + W_);
        xpool[((size_t)n * CIN + c) * (HO * WO) + h2 * WO + w2] = 0.25f * (a.x + a.y + b.x + b.y);
    }
}

// ---------------- K3: XNOR conv (halo image, mask-free hot loop) -> int16 y + fused BN stats ----------------
// bid = n*32 + ocg*4 + strip.
__global__ void __launch_bounds__(256, 4) k_convstat(const unsigned int* __restrict__ abits,
                                                     const unsigned int* __restrict__ wbits,
                                                     const int4* __restrict__ ctab,
                                                     short* __restrict__ y16,
                                                     float* __restrict__ s1, float* __restrict__ s2) {
    __shared__ int red1[32][33], red2[32][33];   // padded: conflict-free
    int bid = blockIdx.x;
    int strip = bid & 3, ocg = (bid >> 2) & 7, n = bid >> 5;
    int tid = threadIdx.x;
    int wave = tid >> 6, lane = tid & 63;
    int oh = strip * 8 + (tid >> 5), ow = tid & 31;

    // 9 unconditional taps, one base addr + immediate offsets (padded image, zero halo)
    const uint4* ab = ((const uint4*)abits) + (size_t)n * PN + (size_t)(2 * oh) * PS + 2 * ow;
    uint4 img[9];
    #pragma unroll
    for (int kh = 0; kh < 3; kh++)
        #pragma unroll
        for (int kw = 0; kw < 3; kw++)
            img[kh * 3 + kw] = ab[kh * PS + kw];

    int fr = (oh == 0) ? -1 : 0;    // top-row taps were pad
    int fc = (ow == 0) ? -1 : 0;    // left-col taps were pad
    int f0 = fr & fc;

    const uint4* wp = ((const uint4*)wbits) + (size_t)ocg * 32 * 9;
    const int4* cp = ctab + ocg * 32;
    short* yp = y16 + (((size_t)n * P_ + ocg * 32) << 10) + strip * 256 + tid;
    #pragma unroll 4
    for (int o = 0; o < 32; o++) {
        int popsum = 0;
        #pragma unroll
        for (int t = 0; t < 9; t++) {
            uint4 a = img[t];
            uint4 w = wp[o * 9 + t];                 // wave-uniform -> scalar load
            popsum += __popc(a.x ^ w.x) + __popc(a.y ^ w.y) +
                      __popc(a.z ^ w.z) + __popc(a.w ^ w.w);
        }
        int4 C = cp[o];                              // wave-uniform -> scalar load
        int s = 1152 - 2 * popsum - (fr & C.x) - (fc & C.y) + (f0 & C.z);
        yp[(size_t)o << 10] = (short)s;
        int vs = s, v2 = s * s;
        vs += __shfl_down(vs, 32); v2 += __shfl_down(v2, 32);
        vs += __shfl_down(vs, 16); v2 += __shfl_down(v2, 16);
        vs += __shfl_down(vs, 8);  v2 += __shfl_down(v2, 8);
        if (lane < 8) { red1[o][wave * 8 + lane] = vs; red2[o][wave * 8 + lane] = v2; }
    }
    __syncthreads();
    if (tid < 64) {
        int o = tid & 31;
        int a = 0;
        if (tid < 32) {
            #pragma unroll
            for (int p = 0; p < 32; p++) a += red1[o][p];
            atomicAdd(s1 + ocg * 32 + o, (float)a);
        } else {
            #pragma unroll
            for (int p = 0; p < 32; p++) a += red2[o][p];
            atomicAdd(s2 + ocg * 32 + o, (float)a);
        }
    }
}

// ---------------- K4: BN finalize+apply + skip + bias2 + PReLU + bias3 -> d_out (R7-proven) ----------------
__global__ void k_epi(const short* __restrict__ y16, const float* __restrict__ xpool,
                      const float* __restrict__ sf,
                      const float* __restrict__ s1, const float* __restrict__ s2,
                      const float* __restrict__ bn_g, const float* __restrict__ bn_b,
                      const float* __restrict__ b2, const float* __restrict__ b3,
                      const float* __restrict__ prelu_a, float* __restrict__ out) {
    int i4 = blockIdx.x * blockDim.x + threadIdx.x;   // 4-pixel index
    int pix4 = i4 & 255;
    int c = (i4 >> 8) & 255;
    int n = i4 >> 16;
    short4 yv = ((const short4*)y16)[i4];
    float4 xv = ((const float4*)xpool)[((n * CIN + (c & 127)) << 8) + pix4];
    const float inv = 1.f / (B_ * HO * WO);
    float sc = sf[c];
    float m = sc * s1[c] * inv;
    float var = fmaf(-m, m, sc * sc * s2[c] * inv);
    float r = rsqrtf(var + 1e-5f) * bn_g[c];
    float add0 = bn_b[c] + b2[n * P_ + c];
    float a = prelu_a[c];
    float b3v = b3[n * P_ + c];
    float o0 = (sc * (float)yv.x - m) * r + add0 + xv.x; o0 = (o0 > 0.f ? o0 : a * o0) + b3v;
    float o1 = (sc * (float)yv.y - m) * r + add0 + xv.y; o1 = (o1 > 0.f ? o1 : a * o1) + b3v;
    float o2 = (sc * (float)yv.z - m) * r + add0 + xv.z; o2 = (o2 > 0.f ? o2 : a * o2) + b3v;
    float o3 = (sc * (float)yv.w - m) * r + add0 + xv.w; o3 = (o3 > 0.f ? o3 : a * o3) + b3v;
    ((float4*)out)[i4] = make_float4(o0, o1, o2, o3);
}

extern "C" void kernel_launch(void* const* d_in, const int* in_sizes, int n_in,
                              void* d_out, int out_size, void* d_ws, size_t ws_size,
                              hipStream_t stream) {
    const float* x      = (const float*)d_in[0];
    const float* emb    = (const float*)d_in[1];
    const float* m1_w   = (const float*)d_in[2];
    const float* m1_b   = (const float*)d_in[3];
    const float* conv_w = (const float*)d_in[4];
    // d_in[5] = conv_b : cancels exactly under training-mode BN, unused
    const float* bn_g   = (const float*)d_in[6];
    const float* bn_b   = (const float*)d_in[7];
    const float* m2_w   = (const float*)d_in[8];
    const float* m2_b   = (const float*)d_in[9];
    const float* prelu_a= (const float*)d_in[10];
    const float* m3_w   = (const float*)d_in[11];
    const float* m3_b   = (const float*)d_in[12];

    float* out = (float*)d_out;   // written once, by k_epi

    // workspace carve-up (f32 words)
    float* wsf = (float*)d_ws;
    float* b1    = wsf;                  // 32*128
    float* b2    = wsf + 4096;           // 32*256
    float* b3    = wsf + 12288;          // 32*256
    float* sf    = wsf + 20480;          // 256
    float* s1    = wsf + 20736;          // 256  (zeroed by k_bw)
    float* s2    = wsf + 20992;          // 256  (zeroed by k_bw)
    int4*  ctab  = (int4*)(wsf + 21248);                  // 256 int4 -> 1024 words
    unsigned int* wbits = (unsigned int*)(wsf + 22272);   // 256*36 u32 -> 9216 words
    unsigned int* abits = (unsigned int*)(wsf + 31488);   // 32*4225 uint4 (padded) = 540800 words
    float* xpool = wsf + 572288;         // 32*128*32*32 f32 (16 MiB)
    short* y16   = (short*)(wsf + 4766592);               // 32*256*1024 i16 (16 MiB)

    k_bw      <<<B_ * 160 + P_ / 2, 256, 0, stream>>>(emb, m1_w, m1_b, m2_w, m2_b, m3_w, m3_b,
                                                      conv_w, b1, b2, b3, sf, wbits, ctab, s1, s2);
    k_prep    <<<B_ * 32, 256, 0, stream>>>(x, b1, abits, xpool);
    k_convstat<<<B_ * 32, 256, 0, stream>>>(abits, wbits, ctab, y16, s1, s2);
    k_epi     <<<(B_ * P_ * HO * WO) / (4 * 256), 256, 0, stream>>>(y16, xpool, sf, s1, s2,
                                                                    bn_g, bn_b, b2, b3, prelu_a, out);
}